// Round 7
// baseline (55.204 us; speedup 1.0000x reference)
//
#include <hip/hip_runtime.h>
#include <hip/hip_cooperative_groups.h>

namespace cg = cooperative_groups;

#define BATCH 2048
#define IND   256
#define OUTD  256

typedef __attribute__((ext_vector_type(8))) short bf16x8;
typedef __attribute__((ext_vector_type(4))) float f32x4;

__device__ __forceinline__ ushort f2bf(float f) {
    uint u = __builtin_bit_cast(uint, f);
    u += 0x7fffu + ((u >> 16) & 1u);          // RNE
    return (ushort)(u >> 16);
}
__device__ __forceinline__ uint pack2(float lo, float hi) {
    return (uint)f2bf(lo) | ((uint)f2bf(hi) << 16);
}

// ---------------- ws layout ----------------
#define BIASOFF (1u << 20)                 // W: [0, 1MB)
#define FOFF    ((1u << 20) + 4096)        // F: 8MB
#define WS_NEED ((size_t)FOFF + (size_t)IND * BATCH * 16)

// features for one x value: [silu, B0..B6] (c7 folded: B7 = 1 - sum -> bias)
__device__ __forceinline__ uint4 feat_pack(float xv) {
    const float u = (xv + 1.0f) * 2.5f;
    float cif = floorf(u);
    cif = fminf(fmaxf(cif, 0.0f), 4.0f);
    const int ci = (int)cif;
    const float f = u - cif, mf = 1.0f - f;
    const float f2 = f * f, f3 = f2 * f;
    const float k6 = 1.0f / 6.0f;
    const float w0 = mf * mf * mf * k6;
    const float w1 = (3.0f * f3 - 6.0f * f2 + 4.0f) * k6;
    const float w3 = f3 * k6;
    const float w2 = 1.0f - w0 - w1 - w3;
    const float sg = __fdividef(xv, 1.0f + __expf(-xv));
    const float B0 = (ci == 0) ? w0 : 0.f;
    const float B1 = (ci == 1) ? w0 : (ci == 0) ? w1 : 0.f;
    const float B2 = (ci == 2) ? w0 : (ci == 1) ? w1 : (ci == 0) ? w2 : 0.f;
    const float B3 = (ci == 3) ? w0 : (ci == 2) ? w1 : (ci == 1) ? w2 : (ci == 0) ? w3 : 0.f;
    const float B4 = (ci == 4) ? w0 : (ci == 3) ? w1 : (ci == 2) ? w2 : (ci == 1) ? w3 : 0.f;
    const float B5 = (ci == 4) ? w1 : (ci == 3) ? w2 : (ci == 2) ? w3 : 0.f;
    const float B6 = (ci == 4) ? w2 : (ci == 3) ? w3 : 0.f;
    uint4 v;
    v.x = pack2(sg, B0); v.y = pack2(B1, B2);
    v.z = pack2(B3, B4); v.w = pack2(B5, B6);
    return v;
}

// ============ single cooperative kernel: prep -> grid.sync -> gemm ============
// 256 blocks x 1024 threads (1 block/CU, all co-resident).
// Phase 1: block bid preps F rows b0p=(bid&7)*256+(bid>>3)*8 (XCD-aligned so phase-2
//          A-reads are L2-local), W row i=bid, bias (blocks 0..31).
// Phase 2: R5's register-direct GEMM. Block: 32M x 64N; 16 waves = kq(8 K-split) x nh(2).
__global__ __launch_bounds__(1024, 4) void kan_one(
    const float* __restrict__ x, const float* __restrict__ coef,
    const float* __restrict__ sb, const float* __restrict__ ss,
    const float* __restrict__ mask,
    uint4* __restrict__ W, float* __restrict__ bias, uint4* __restrict__ F,
    float* __restrict__ out)
{
    __shared__ float shm[2 * 7 * 1024];   // 56KB: phase1 xs/part, phase2 reduce

    const int bid = blockIdx.x, tid = threadIdx.x;
    const int xcd = bid & 7;

    // ================= phase 1: prep =================
    {
        const int b0p = xcd * 256 + (bid >> 3) * 8;
        float* xs = shm;                              // [8][258]
        {
            const int row = tid >> 7, c2 = (tid & 127) * 2;
            const float2 v = *reinterpret_cast<const float2*>(
                x + (size_t)(b0p + row) * IND + c2);
            xs[row * 258 + c2]     = v.x;
            xs[row * 258 + c2 + 1] = v.y;
        }
        if (tid < 256) {                              // W row i = bid
            const int io = bid * OUTD + tid;
            const float m = mask[io], b = sb[io], sp = ss[io];
            const float4* cp = reinterpret_cast<const float4*>(coef + (size_t)io * 8);
            const float4 c0 = cp[0], c1 = cp[1];
            const float wb = m * b, wsp = m * sp;
            const float c7 = c1.w;
            uint4 w;
            w.x = pack2(wb,                wsp * (c0.x - c7));
            w.y = pack2(wsp * (c0.y - c7), wsp * (c0.z - c7));
            w.z = pack2(wsp * (c0.w - c7), wsp * (c1.x - c7));
            w.w = pack2(wsp * (c1.y - c7), wsp * (c1.z - c7));
            W[io] = w;
        }
        __syncthreads();
#pragma unroll
        for (int p = 0; p < 2; ++p) {                 // F: 2 packs/thread
            const int q = p * 1024 + tid;
            const int i = q >> 3, b = q & 7;
            F[(size_t)i * BATCH + b0p + b] = feat_pack(xs[b * 258 + i]);
        }
        if (bid < 32 && tid < 256) {                  // bias partials
            float* part = shm + 2080;                 // [32][8], after xs (2064)
            const int o0b = bid * 8, ol = tid & 7, ig = tid >> 3;
            float s = 0.f;
#pragma unroll
            for (int ii = 0; ii < 8; ++ii) {
                const int i = ig * 8 + ii;
                const int io = i * OUTD + o0b + ol;
                s += mask[io] * ss[io] * coef[(size_t)io * 8 + 7];
            }
            part[ig * 8 + ol] = s;
        }
        __syncthreads();
        if (bid < 32 && tid < 8) {
            const float* part = shm + 2080;
            float acc = 0.f;
#pragma unroll
            for (int g2 = 0; g2 < 32; ++g2) acc += part[g2 * 8 + tid];
            bias[bid * 8 + tid] = acc;
        }
    }

    cg::this_grid().sync();

    // ================= phase 2: register-direct GEMM =================
    const int lane = tid & 63, wid = tid >> 6;
    const int nh = wid & 1, kq = wid >> 1;            // kq 0..7
    const int r = lane & 15, g = lane >> 4;
    const int b0 = xcd * 256 + ((bid >> 3) & 7) * 32; // XCD-local F slice
    const int o0 = (bid >> 6) * 64;

    const uint4* pA = F + (size_t)(kq * 32 + g) * BATCH + b0 + r;
    const uint4* pB = W + (size_t)(kq * 32 + g) * OUTD + o0 + nh * 32 + r;

    f32x4 acc[2][2] = {};
    bf16x8 aC0, aC1, bC0, bC1, aN0, aN1, bN0, bN1;

#define LD(A0, A1, B0_, B1_, t)                                                        \
    {                                                                                  \
        A0  = *reinterpret_cast<const bf16x8*>(pA + (size_t)(4 * (t)) * BATCH);        \
        A1  = *reinterpret_cast<const bf16x8*>(pA + (size_t)(4 * (t)) * BATCH + 16);   \
        B0_ = *reinterpret_cast<const bf16x8*>(pB + (size_t)(4 * (t)) * OUTD);         \
        B1_ = *reinterpret_cast<const bf16x8*>(pB + (size_t)(4 * (t)) * OUTD + 16);    \
    }
#define MM(A0, A1, B0_, B1_)                                                           \
    {                                                                                  \
        acc[0][0] = __builtin_amdgcn_mfma_f32_16x16x32_bf16(A0, B0_, acc[0][0], 0, 0, 0); \
        acc[0][1] = __builtin_amdgcn_mfma_f32_16x16x32_bf16(A0, B1_, acc[0][1], 0, 0, 0); \
        acc[1][0] = __builtin_amdgcn_mfma_f32_16x16x32_bf16(A1, B0_, acc[1][0], 0, 0, 0); \
        acc[1][1] = __builtin_amdgcn_mfma_f32_16x16x32_bf16(A1, B1_, acc[1][1], 0, 0, 0); \
    }

    LD(aC0, aC1, bC0, bC1, 0);
#pragma unroll
    for (int t = 0; t < 8; t += 2) {
        if (t + 1 < 8) LD(aN0, aN1, bN0, bN1, t + 1);
        MM(aC0, aC1, bC0, bC1);
        if (t + 2 < 8) LD(aC0, aC1, bC0, bC1, t + 2);
        if (t + 1 < 8) MM(aN0, aN1, bN0, bN1);
    }
#undef LD
#undef MM

    // ---- epilogue: 8-way K-reduce per N-half via LDS ----
    __syncthreads();                                  // shm free for reduce
    float* red = shm;                                 // [2][7][1024]
    if (kq > 0) {
        float* dst = red + (size_t)(nh * 7 + kq - 1) * 1024;
#pragma unroll
        for (int mf = 0; mf < 2; ++mf)
#pragma unroll
            for (int nf = 0; nf < 2; ++nf)
                *reinterpret_cast<f32x4*>(dst + (mf * 2 + nf) * 256 + lane * 4) = acc[mf][nf];
    }
    __syncthreads();
    if (kq == 0) {
#pragma unroll
        for (int mf = 0; mf < 2; ++mf)
#pragma unroll
            for (int nf = 0; nf < 2; ++nf) {
                f32x4 s = acc[mf][nf];
                const int sl = (mf * 2 + nf) * 256 + lane * 4;
#pragma unroll
                for (int kk = 0; kk < 7; ++kk) {
                    const f32x4 v = *reinterpret_cast<const f32x4*>(
                        red + (size_t)(nh * 7 + kk) * 1024 + sl);
                    s.x += v.x; s.y += v.y; s.z += v.z; s.w += v.w;
                }
                const int col  = o0 + nh * 32 + nf * 16 + r;
                const int row0 = b0 + mf * 16 + g * 4;
                const float bv = bias[col];
#pragma unroll
                for (int e = 0; e < 4; ++e)
                    out[(size_t)(row0 + e) * OUTD + col] = s[e] + bv;
            }
    }
}

// ============ fallback path A (R5 two-kernel, used if coop launch fails) ============
__global__ __launch_bounds__(256) void kan_prep(
    const float* __restrict__ x, const float* __restrict__ coef,
    const float* __restrict__ sb, const float* __restrict__ ss,
    const float* __restrict__ mask,
    uint4* __restrict__ W, float* __restrict__ bias, uint4* __restrict__ F)
{
    const int bid = blockIdx.x, tid = threadIdx.x;
    __shared__ float xt[4 * 260];
    __shared__ float part[32][8];
    const int b0 = bid * 4;
    {
        const int row = tid >> 6, c4 = (tid & 63) * 4;
        const float4 v = *reinterpret_cast<const float4*>(
            x + (size_t)(b0 + row) * IND + c4);
        xt[row * 260 + c4 + 0] = v.x;
        xt[row * 260 + c4 + 1] = v.y;
        xt[row * 260 + c4 + 2] = v.z;
        xt[row * 260 + c4 + 3] = v.w;
    }
    if (tid < 128) {
        const int i = bid >> 1, o = (bid & 1) * 128 + tid;
        const int io = i * OUTD + o;
        const float m = mask[io], b = sb[io], sp = ss[io];
        const float4* cp = reinterpret_cast<const float4*>(coef + (size_t)io * 8);
        const float4 c0 = cp[0], c1 = cp[1];
        const float wb = m * b, wsp = m * sp;
        const float c7 = c1.w;
        uint4 w;
        w.x = pack2(wb,                wsp * (c0.x - c7));
        w.y = pack2(wsp * (c0.y - c7), wsp * (c0.z - c7));
        w.z = pack2(wsp * (c0.w - c7), wsp * (c1.x - c7));
        w.w = pack2(wsp * (c1.y - c7), wsp * (c1.z - c7));
        W[io] = w;
    }
    __syncthreads();
#pragma unroll
    for (int p = 0; p < 4; ++p) {
        const int q = p * 256 + tid;
        const int i = q >> 2, b = q & 3;
        F[(size_t)i * BATCH + b0 + b] = feat_pack(xt[b * 260 + i]);
    }
    if (bid >= 480) {
        const int o0 = (bid - 480) * 8;
        const int ol = tid & 7, ig = tid >> 3;
        float s = 0.f;
#pragma unroll
        for (int ii = 0; ii < 8; ++ii) {
            const int i = ig * 8 + ii;
            const int io = i * OUTD + o0 + ol;
            s += mask[io] * ss[io] * coef[(size_t)io * 8 + 7];
        }
        part[ig][ol] = s;
        __syncthreads();
        if (tid < 8) {
            float acc = 0.f;
#pragma unroll
            for (int g2 = 0; g2 < 32; ++g2) acc += part[g2][tid];
            bias[o0 + tid] = acc;
        }
    }
}

__global__ __launch_bounds__(1024, 4) void kan_gemm(
    const uint4* __restrict__ F, const uint4* __restrict__ W,
    const float* __restrict__ bias, float* __restrict__ out)
{
    const int tid  = threadIdx.x;
    const int lane = tid & 63, wid = tid >> 6;
    const int nh = wid & 1, kq = wid >> 1;
    const int r = lane & 15, g = lane >> 4;
    const int b0 = (blockIdx.x >> 2) * 32;
    const int o0 = (blockIdx.x & 3) * 64;

    const uint4* pA = F + (size_t)(kq * 32 + g) * BATCH + b0 + r;
    const uint4* pB = W + (size_t)(kq * 32 + g) * OUTD + o0 + nh * 32 + r;

    f32x4 acc[2][2] = {};
    bf16x8 aC0, aC1, bC0, bC1, aN0, aN1, bN0, bN1;

#define LD(A0, A1, B0_, B1_, t)                                                        \
    {                                                                                  \
        A0  = *reinterpret_cast<const bf16x8*>(pA + (size_t)(4 * (t)) * BATCH);        \
        A1  = *reinterpret_cast<const bf16x8*>(pA + (size_t)(4 * (t)) * BATCH + 16);   \
        B0_ = *reinterpret_cast<const bf16x8*>(pB + (size_t)(4 * (t)) * OUTD);         \
        B1_ = *reinterpret_cast<const bf16x8*>(pB + (size_t)(4 * (t)) * OUTD + 16);    \
    }
#define MM(A0, A1, B0_, B1_)                                                           \
    {                                                                                  \
        acc[0][0] = __builtin_amdgcn_mfma_f32_16x16x32_bf16(A0, B0_, acc[0][0], 0, 0, 0); \
        acc[0][1] = __builtin_amdgcn_mfma_f32_16x16x32_bf16(A0, B1_, acc[0][1], 0, 0, 0); \
        acc[1][0] = __builtin_amdgcn_mfma_f32_16x16x32_bf16(A1, B0_, acc[1][0], 0, 0, 0); \
        acc[1][1] = __builtin_amdgcn_mfma_f32_16x16x32_bf16(A1, B1_, acc[1][1], 0, 0, 0); \
    }

    LD(aC0, aC1, bC0, bC1, 0);
#pragma unroll
    for (int t = 0; t < 8; t += 2) {
        if (t + 1 < 8) LD(aN0, aN1, bN0, bN1, t + 1);
        MM(aC0, aC1, bC0, bC1);
        if (t + 2 < 8) LD(aC0, aC1, bC0, bC1, t + 2);
        if (t + 1 < 8) MM(aN0, aN1, bN0, bN1);
    }
#undef LD
#undef MM

    __shared__ float red[2][7][1024];
    if (kq > 0) {
        float* dst = &red[nh][kq - 1][0];
#pragma unroll
        for (int mf = 0; mf < 2; ++mf)
#pragma unroll
            for (int nf = 0; nf < 2; ++nf)
                *reinterpret_cast<f32x4*>(dst + (mf * 2 + nf) * 256 + lane * 4) = acc[mf][nf];
    }
    __syncthreads();
    if (kq == 0) {
#pragma unroll
        for (int mf = 0; mf < 2; ++mf)
#pragma unroll
            for (int nf = 0; nf < 2; ++nf) {
                f32x4 s = acc[mf][nf];
                const int sl = (mf * 2 + nf) * 256 + lane * 4;
#pragma unroll
                for (int kk = 0; kk < 7; ++kk) {
                    const f32x4 v = *reinterpret_cast<const f32x4*>(&red[nh][kk][0] + sl);
                    s.x += v.x; s.y += v.y; s.z += v.z; s.w += v.w;
                }
                const int col  = o0 + nh * 32 + nf * 16 + r;
                const int row0 = b0 + mf * 16 + g * 4;
                const float bv = bias[col];
#pragma unroll
                for (int e = 0; e < 4; ++e)
                    out[(size_t)(row0 + e) * OUTD + col] = s[e] + bv;
            }
    }
}

// ============ fallback path B (fused, used only if ws too small) ============
#define KPI  16
#define IPC  8
#define KC   (IPC * KPI)

__global__ __launch_bounds__(256, 2) void kan_mfma(
    const float* __restrict__ x, const float* __restrict__ coef,
    const float* __restrict__ scale_base, const float* __restrict__ scale_sp,
    const float* __restrict__ mask, float* __restrict__ out)
{
    const int tid = threadIdx.x;
    const int b0 = blockIdx.x * 32, o0 = blockIdx.y * 32;
    __shared__ uint Fa[32 * KC / 2];
    __shared__ uint Wt2[32 * KC / 2];
    for (int j = tid; j < 32 * KC / 2; j += 256) { Fa[j] = 0u; Wt2[j] = 0u; }
    const int lane = tid & 63, wid = tid >> 6;
    const int wmv = (wid >> 1) * 16, wnv = (wid & 1) * 16;
    f32x4 acc = {0.f, 0.f, 0.f, 0.f};
    const int fb = tid & 31, il = tid >> 5;
    for (int ic = 0; ic < IND / IPC; ++ic) {
        const int i = ic * IPC + il;
        __syncthreads();
        {
            const uint4 fp = feat_pack(x[(b0 + fb) * IND + i]);
            const int base = fb * (KC / 2) + il * (KPI / 2);
            const int sw = (fb & 7) << 2;
            Fa[(base + 0) ^ sw] = fp.x; Fa[(base + 1) ^ sw] = fp.y;
            Fa[(base + 2) ^ sw] = fp.z; Fa[(base + 3) ^ sw] = fp.w;
            ((ushort*)Fa)[2 * ((base + 4) ^ sw)] = 0;
        }
        {
            const int io = i * OUTD + o0 + fb;
            const float m = mask[io];
            const float wb = scale_base[io] * m, wsv = scale_sp[io] * m;
            const float4* cp = reinterpret_cast<const float4*>(coef + (size_t)io * 8);
            const float4 c0 = cp[0], c1 = cp[1];
            const float c7 = c1.w;
            const int base = fb * (KC / 2) + il * (KPI / 2);
            const int sw = (fb & 7) << 2;
            Wt2[(base + 0) ^ sw] = pack2(wb, wsv * (c0.x - c7));
            Wt2[(base + 1) ^ sw] = pack2(wsv * (c0.y - c7), wsv * (c0.z - c7));
            Wt2[(base + 2) ^ sw] = pack2(wsv * (c0.w - c7), wsv * (c1.x - c7));
            Wt2[(base + 3) ^ sw] = pack2(wsv * (c1.y - c7), wsv * (c1.z - c7));
            ((ushort*)Wt2)[2 * ((base + 4) ^ sw)] = 0;
        }
        __syncthreads();
        {
            const ushort* fs = (const ushort*)Fa;
            const ushort* wsd = (const ushort*)Wt2;
            const int ar = wmv + (lane & 15), br = wnv + (lane & 15);
            const int kg = (lane >> 4) * 8;
#pragma unroll
            for (int ksi = 0; ksi < 4; ++ksi) {
                const int ka = ksi * 32 + kg;
                const int ia = (ar * KC + ka) ^ ((ar & 7) << 3);
                const int ib = (br * KC + ka) ^ ((br & 7) << 3);
                bf16x8 a = *reinterpret_cast<const bf16x8*>(fs + ia);
                bf16x8 b = *reinterpret_cast<const bf16x8*>(wsd + ib);
                acc = __builtin_amdgcn_mfma_f32_16x16x32_bf16(a, b, acc, 0, 0, 0);
            }
        }
    }
    const int col = o0 + wnv + (lane & 15);
    const int row0 = b0 + wmv + ((lane >> 4) << 2);
    float bv = 0.f;
    for (int i = 0; i < IND; ++i) {
        const int io = i * OUTD + col;
        bv += mask[io] * scale_sp[io] * coef[(size_t)io * 8 + 7];
    }
#pragma unroll
    for (int rr = 0; rr < 4; ++rr)
        out[(size_t)(row0 + rr) * OUTD + col] = acc[rr] + bv;
}

extern "C" void kernel_launch(void* const* d_in, const int* in_sizes, int n_in,
                              void* d_out, int out_size, void* d_ws, size_t ws_size,
                              hipStream_t stream) {
    const float* x          = (const float*)d_in[0];
    const float* coef       = (const float*)d_in[2];
    const float* scale_base = (const float*)d_in[3];
    const float* scale_sp   = (const float*)d_in[4];
    const float* mask       = (const float*)d_in[5];
    float* out = (float*)d_out;

    if (ws_size >= WS_NEED) {
        uint4* W    = (uint4*)d_ws;
        float* bias = (float*)((char*)d_ws + BIASOFF);
        uint4* F    = (uint4*)((char*)d_ws + FOFF);

        void* args[] = {(void*)&x, (void*)&coef, (void*)&scale_base, (void*)&scale_sp,
                        (void*)&mask, (void*)&W, (void*)&bias, (void*)&F, (void*)&out};
        hipError_t err = hipLaunchCooperativeKernel(
            (const void*)kan_one, dim3(256), dim3(1024), args, 0, stream);
        if (err != hipSuccess) {
            // fallback: proven R5 two-kernel path
            kan_prep<<<512, 256, 0, stream>>>(x, coef, scale_base, scale_sp, mask, W, bias, F);
            kan_gemm<<<256, 1024, 0, stream>>>(F, W, bias, out);
        }
    } else {
        kan_mfma<<<dim3(BATCH / 32, OUTD / 32), 256, 0, stream>>>(
            x, coef, scale_base, scale_sp, mask, out);
    }
}

// Round 8
// 18.273 us; speedup vs baseline: 3.0210x; 3.0210x over previous
//
#include <hip/hip_runtime.h>

#define BATCH 2048
#define IND   256
#define OUTD  256

typedef __attribute__((ext_vector_type(8))) short bf16x8;
typedef __attribute__((ext_vector_type(4))) float f32x4;

__device__ __forceinline__ ushort f2bf(float f) {
    uint u = __builtin_bit_cast(uint, f);
    u += 0x7fffu + ((u >> 16) & 1u);          // RNE
    return (ushort)(u >> 16);
}
__device__ __forceinline__ uint pack2(float lo, float hi) {
    return (uint)f2bf(lo) | ((uint)f2bf(hi) << 16);
}

// ---------------- ws layout ----------------
#define BIASOFF (1u << 20)                 // W: [0, 1MB)
#define FOFF    ((1u << 20) + 4096)        // F: 8MB
#define WS_NEED ((size_t)FOFF + (size_t)IND * BATCH * 16)

// features for one x value: [silu, B0..B6] (c7 folded: B7 = 1 - sum -> bias)
__device__ __forceinline__ uint4 feat_pack(float xv) {
    const float u = (xv + 1.0f) * 2.5f;
    float cif = floorf(u);
    cif = fminf(fmaxf(cif, 0.0f), 4.0f);
    const int ci = (int)cif;
    const float f = u - cif, mf = 1.0f - f;
    const float f2 = f * f, f3 = f2 * f;
    const float k6 = 1.0f / 6.0f;
    const float w0 = mf * mf * mf * k6;
    const float w1 = (3.0f * f3 - 6.0f * f2 + 4.0f) * k6;
    const float w3 = f3 * k6;
    const float w2 = 1.0f - w0 - w1 - w3;
    const float sg = __fdividef(xv, 1.0f + __expf(-xv));
    const float B0 = (ci == 0) ? w0 : 0.f;
    const float B1 = (ci == 1) ? w0 : (ci == 0) ? w1 : 0.f;
    const float B2 = (ci == 2) ? w0 : (ci == 1) ? w1 : (ci == 0) ? w2 : 0.f;
    const float B3 = (ci == 3) ? w0 : (ci == 2) ? w1 : (ci == 1) ? w2 : (ci == 0) ? w3 : 0.f;
    const float B4 = (ci == 4) ? w0 : (ci == 3) ? w1 : (ci == 2) ? w2 : (ci == 1) ? w3 : 0.f;
    const float B5 = (ci == 4) ? w1 : (ci == 3) ? w2 : (ci == 2) ? w3 : 0.f;
    const float B6 = (ci == 4) ? w2 : (ci == 3) ? w3 : 0.f;
    uint4 v;
    v.x = pack2(sg, B0); v.y = pack2(B1, B2);
    v.z = pack2(B3, B4); v.w = pack2(B5, B6);
    return v;
}

// ============ kernel 1: prep — 512 balanced blocks x 256 ============
// F rows XCD-aligned: block bid writes b-rows [(bid&7)*256 + (bid>>3)*4, +4),
// so gemm block with xcd=bid&7 reads F rows its own XCD's L2 already owns.
// Plus W pack for one (i, o-half); blocks 480..511 also compute bias (8 o's each).
__global__ __launch_bounds__(256) void kan_prep(
    const float* __restrict__ x, const float* __restrict__ coef,
    const float* __restrict__ sb, const float* __restrict__ ss,
    const float* __restrict__ mask,
    uint4* __restrict__ W, float* __restrict__ bias, uint4* __restrict__ F)
{
    const int bid = blockIdx.x, tid = threadIdx.x;
    __shared__ float xt[4 * 260];
    __shared__ float part[32][8];

    const int b0 = (bid & 7) * 256 + (bid >> 3) * 4;
    {
        const int row = tid >> 6, c4 = (tid & 63) * 4;
        const float4 v = *reinterpret_cast<const float4*>(
            x + (size_t)(b0 + row) * IND + c4);
        xt[row * 260 + c4 + 0] = v.x;
        xt[row * 260 + c4 + 1] = v.y;
        xt[row * 260 + c4 + 2] = v.z;
        xt[row * 260 + c4 + 3] = v.w;
    }

    // ---- W: i = bid>>1, o-half = (bid&1)*128 ----
    if (tid < 128) {
        const int i = bid >> 1, o = (bid & 1) * 128 + tid;
        const int io = i * OUTD + o;
        const float m = mask[io], b = sb[io], sp = ss[io];
        const float4* cp = reinterpret_cast<const float4*>(coef + (size_t)io * 8);
        const float4 c0 = cp[0], c1 = cp[1];
        const float wb = m * b, wsp = m * sp;
        const float c7 = c1.w;
        uint4 w;
        w.x = pack2(wb,                wsp * (c0.x - c7));
        w.y = pack2(wsp * (c0.y - c7), wsp * (c0.z - c7));
        w.z = pack2(wsp * (c0.w - c7), wsp * (c1.x - c7));
        w.w = pack2(wsp * (c1.y - c7), wsp * (c1.z - c7));
        W[io] = w;
    }
    __syncthreads();

    // ---- F: 4 packs/thread, write F[i][b] ----
#pragma unroll
    for (int p = 0; p < 4; ++p) {
        const int q = p * 256 + tid;
        const int i = q >> 2, b = q & 3;
        F[(size_t)i * BATCH + b0 + b] = feat_pack(xt[b * 260 + i]);
    }

    // ---- bias: last 32 blocks, 8 o's each ----
    if (bid >= 480) {
        const int o0 = (bid - 480) * 8;
        const int ol = tid & 7, ig = tid >> 3;
        float s = 0.f;
#pragma unroll
        for (int ii = 0; ii < 8; ++ii) {
            const int i = ig * 8 + ii;
            const int io = i * OUTD + o0 + ol;
            s += mask[io] * ss[io] * coef[(size_t)io * 8 + 7];
        }
        part[ig][ol] = s;
        __syncthreads();
        if (tid < 8) {
            float acc = 0.f;
#pragma unroll
            for (int g2 = 0; g2 < 32; ++g2) acc += part[g2][tid];
            bias[o0 + tid] = acc;
        }
    }
}

// ============ kernel 2: register-direct GEMM, depth-4 prefetch ============
// 256 blocks x 512 threads (2 blocks/CU, 4 waves/SIMD). Block tile 32M x 64N.
// xcd = bid&7 -> m-tile = xcd*8 + (q>>2), n-tile = q&3 (q = bid>>3):
//   each XCD reads only its 1MB F-slice + 1MB W (both L2-resident).
// 8 waves = kq(4-way K-split over i) x nh(2 N-halves). Wave tile 32x32, 16 t-steps.
__global__ __launch_bounds__(512, 4) void kan_gemm(
    const uint4* __restrict__ F, const uint4* __restrict__ W,
    const float* __restrict__ bias, float* __restrict__ out)
{
    const int tid  = threadIdx.x;
    const int lane = tid & 63, wid = tid >> 6;
    const int nh = wid & 1, kq = wid >> 1;            // kq 0..3
    const int r = lane & 15, g = lane >> 4;
    const int bid = blockIdx.x;
    const int q = bid >> 3;
    const int b0 = ((bid & 7) * 8 + (q >> 2)) * 32;   // XCD-local m-tile
    const int o0 = (q & 3) * 64;

    const uint4* pA = F + (size_t)(kq * 64 + g) * BATCH + b0 + r;
    const uint4* pB = W + (size_t)(kq * 64 + g) * OUTD + o0 + nh * 32 + r;

    f32x4 acc[2][2] = {};
    // 4-slot rotating fragment buffers (all static indices)
    bf16x8 a0_0, a1_0, b0_0, b1_0;
    bf16x8 a0_1, a1_1, b0_1, b1_1;
    bf16x8 a0_2, a1_2, b0_2, b1_2;
    bf16x8 a0_3, a1_3, b0_3, b1_3;

#define LDS_(s, t)                                                                     \
    {                                                                                  \
        a0_##s = *reinterpret_cast<const bf16x8*>(pA + (size_t)(4 * (t)) * BATCH);     \
        a1_##s = *reinterpret_cast<const bf16x8*>(pA + (size_t)(4 * (t)) * BATCH + 16);\
        b0_##s = *reinterpret_cast<const bf16x8*>(pB + (size_t)(4 * (t)) * OUTD);      \
        b1_##s = *reinterpret_cast<const bf16x8*>(pB + (size_t)(4 * (t)) * OUTD + 16); \
    }
#define MM_(s)                                                                         \
    {                                                                                  \
        acc[0][0] = __builtin_amdgcn_mfma_f32_16x16x32_bf16(a0_##s, b0_##s, acc[0][0], 0, 0, 0); \
        acc[0][1] = __builtin_amdgcn_mfma_f32_16x16x32_bf16(a0_##s, b1_##s, acc[0][1], 0, 0, 0); \
        acc[1][0] = __builtin_amdgcn_mfma_f32_16x16x32_bf16(a1_##s, b0_##s, acc[1][0], 0, 0, 0); \
        acc[1][1] = __builtin_amdgcn_mfma_f32_16x16x32_bf16(a1_##s, b1_##s, acc[1][1], 0, 0, 0); \
    }

    LDS_(0, 0)  LDS_(1, 1)  LDS_(2, 2)  LDS_(3, 3)
    MM_(0) LDS_(0, 4)   MM_(1) LDS_(1, 5)   MM_(2) LDS_(2, 6)   MM_(3) LDS_(3, 7)
    MM_(0) LDS_(0, 8)   MM_(1) LDS_(1, 9)   MM_(2) LDS_(2, 10)  MM_(3) LDS_(3, 11)
    MM_(0) LDS_(0, 12)  MM_(1) LDS_(1, 13)  MM_(2) LDS_(2, 14)  MM_(3) LDS_(3, 15)
    MM_(0) MM_(1) MM_(2) MM_(3)
#undef LDS_
#undef MM_

    // ---- epilogue: 4-way K-reduce per N-half via LDS, add bias, store ----
    __shared__ float red[2][3][1024];   // 24 KB
    if (kq > 0) {
        float* dst = &red[nh][kq - 1][0];
#pragma unroll
        for (int mf = 0; mf < 2; ++mf)
#pragma unroll
            for (int nf = 0; nf < 2; ++nf)
                *reinterpret_cast<f32x4*>(dst + (mf * 2 + nf) * 256 + lane * 4) = acc[mf][nf];
    }
    __syncthreads();
    if (kq == 0) {
#pragma unroll
        for (int mf = 0; mf < 2; ++mf)
#pragma unroll
            for (int nf = 0; nf < 2; ++nf) {
                f32x4 s = acc[mf][nf];
                const int sl = (mf * 2 + nf) * 256 + lane * 4;
#pragma unroll
                for (int kk = 0; kk < 3; ++kk) {
                    const f32x4 v = *reinterpret_cast<const f32x4*>(&red[nh][kk][0] + sl);
                    s.x += v.x; s.y += v.y; s.z += v.z; s.w += v.w;
                }
                const int col  = o0 + nh * 32 + nf * 16 + r;
                const int row0 = b0 + mf * 16 + g * 4;
                const float bv = bias[col];
#pragma unroll
                for (int e = 0; e < 4; ++e)
                    out[(size_t)(row0 + e) * OUTD + col] = s[e] + bv;
            }
    }
}

// ============ fallback (used only if ws too small) ============
#define KPI  16
#define IPC  8
#define KC   (IPC * KPI)

__global__ __launch_bounds__(256, 2) void kan_mfma(
    const float* __restrict__ x, const float* __restrict__ coef,
    const float* __restrict__ scale_base, const float* __restrict__ scale_sp,
    const float* __restrict__ mask, float* __restrict__ out)
{
    const int tid = threadIdx.x;
    const int b0 = blockIdx.x * 32, o0 = blockIdx.y * 32;
    __shared__ uint Fa[32 * KC / 2];
    __shared__ uint Wt2[32 * KC / 2];
    for (int j = tid; j < 32 * KC / 2; j += 256) { Fa[j] = 0u; Wt2[j] = 0u; }
    const int lane = tid & 63, wid = tid >> 6;
    const int wmv = (wid >> 1) * 16, wnv = (wid & 1) * 16;
    f32x4 acc = {0.f, 0.f, 0.f, 0.f};
    const int fb = tid & 31, il = tid >> 5;
    for (int ic = 0; ic < IND / IPC; ++ic) {
        const int i = ic * IPC + il;
        __syncthreads();
        {
            const uint4 fp = feat_pack(x[(b0 + fb) * IND + i]);
            const int base = fb * (KC / 2) + il * (KPI / 2);
            const int sw = (fb & 7) << 2;
            Fa[(base + 0) ^ sw] = fp.x; Fa[(base + 1) ^ sw] = fp.y;
            Fa[(base + 2) ^ sw] = fp.z; Fa[(base + 3) ^ sw] = fp.w;
            ((ushort*)Fa)[2 * ((base + 4) ^ sw)] = 0;
        }
        {
            const int io = i * OUTD + o0 + fb;
            const float m = mask[io];
            const float wb = scale_base[io] * m, wsv = scale_sp[io] * m;
            const float4* cp = reinterpret_cast<const float4*>(coef + (size_t)io * 8);
            const float4 c0 = cp[0], c1 = cp[1];
            const float c7 = c1.w;
            const int base = fb * (KC / 2) + il * (KPI / 2);
            const int sw = (fb & 7) << 2;
            Wt2[(base + 0) ^ sw] = pack2(wb, wsv * (c0.x - c7));
            Wt2[(base + 1) ^ sw] = pack2(wsv * (c0.y - c7), wsv * (c0.z - c7));
            Wt2[(base + 2) ^ sw] = pack2(wsv * (c0.w - c7), wsv * (c1.x - c7));
            Wt2[(base + 3) ^ sw] = pack2(wsv * (c1.y - c7), wsv * (c1.z - c7));
            ((ushort*)Wt2)[2 * ((base + 4) ^ sw)] = 0;
        }
        __syncthreads();
        {
            const ushort* fs = (const ushort*)Fa;
            const ushort* wsd = (const ushort*)Wt2;
            const int ar = wmv + (lane & 15), br = wnv + (lane & 15);
            const int kg = (lane >> 4) * 8;
#pragma unroll
            for (int ksi = 0; ksi < 4; ++ksi) {
                const int ka = ksi * 32 + kg;
                const int ia = (ar * KC + ka) ^ ((ar & 7) << 3);
                const int ib = (br * KC + ka) ^ ((br & 7) << 3);
                bf16x8 a = *reinterpret_cast<const bf16x8*>(fs + ia);
                bf16x8 b = *reinterpret_cast<const bf16x8*>(wsd + ib);
                acc = __builtin_amdgcn_mfma_f32_16x16x32_bf16(a, b, acc, 0, 0, 0);
            }
        }
    }
    const int col = o0 + wnv + (lane & 15);
    const int row0 = b0 + wmv + ((lane >> 4) << 2);
    float bv = 0.f;
    for (int i = 0; i < IND; ++i) {
        const int io = i * OUTD + col;
        bv += mask[io] * scale_sp[io] * coef[(size_t)io * 8 + 7];
    }
#pragma unroll
    for (int rr = 0; rr < 4; ++rr)
        out[(size_t)(row0 + rr) * OUTD + col] = acc[rr] + bv;
}

extern "C" void kernel_launch(void* const* d_in, const int* in_sizes, int n_in,
                              void* d_out, int out_size, void* d_ws, size_t ws_size,
                              hipStream_t stream) {
    const float* x          = (const float*)d_in[0];
    const float* coef       = (const float*)d_in[2];
    const float* scale_base = (const float*)d_in[3];
    const float* scale_sp   = (const float*)d_in[4];
    const float* mask       = (const float*)d_in[5];
    float* out = (float*)d_out;

    if (ws_size >= WS_NEED) {
        uint4* W    = (uint4*)d_ws;
        float* bias = (float*)((char*)d_ws + BIASOFF);
        uint4* F    = (uint4*)((char*)d_ws + FOFF);
        kan_prep<<<512, 256, 0, stream>>>(x, coef, scale_base, scale_sp, mask, W, bias, F);
        kan_gemm<<<256, 512, 0, stream>>>(F, W, bias, out);
    } else {
        kan_mfma<<<dim3(BATCH / 32, OUTD / 32), 256, 0, stream>>>(
            x, coef, scale_base, scale_sp, mask, out);
    }
}